// Round 16
// baseline (366.278 us; speedup 1.0000x reference)
//
#include <hip/hip_runtime.h>

typedef short bf16x8 __attribute__((ext_vector_type(8)));
typedef float f32x4 __attribute__((ext_vector_type(4)));
typedef unsigned short u16;
typedef unsigned int u32;

#define NN 100000
#define NE 600000
#define PART 12500        // NN / 8
#define ECH 4688          // ceil(NE / 128)

__device__ __forceinline__ u16 f2b(float f) {
    u32 u = __float_as_uint(f);
    return (u16)((u + 0x7FFFu + ((u >> 16) & 1u)) >> 16);
}

// ---------------- XCD-partitioned degree count, standalone co-resident grid ----------------
// MUST be its own dispatch: fusing with the conv_x stream evicts the dirty counter
// lines from L2 between atomics (r15: +37MB writeback, 64us). Standalone, lines stay
// resident in their owning XCD's L2 for the whole dispatch (r8: <62us, low WRITE).
__global__ __launch_bounds__(256) void deg_part(
    const int* __restrict__ d0, const int* __restrict__ d1,
    int* __restrict__ g0, int* __restrict__ g1)
{
    int part = blockIdx.x & 7;
    int sub = blockIdx.x >> 3;                // 0..255
    int rel = sub & 1;
    int chunk = sub >> 1;                     // 0..127
    const int lo = part * PART, hi = lo + PART;
    const int* d = rel ? d1 : d0;
    int* g = rel ? g1 : g0;
    const int e0 = chunk * ECH;
    const int e1 = min(e0 + ECH, NE);
    for (int e = e0 + threadIdx.x; e < e1; e += 256) {
        int dd = d[e];
        if (dd >= lo && dd < hi) atomicAdd(&g[dd], 1);
    }
}

// ---------------- fused setup: x->bf16 | weight prep (pure streaming) ----------------
// wts layout (u16): 0 Wsum0T[128][128], 16384 Wn0r0T, 32768 Wn0r1T,
//   49152 Wp0T[128][128], 65536 Wp1T, 81920 Wsum1T[64][128], 90112 Wn1r0T, 98304 Wn1r1T
__global__ void fused_setup(
    const float* __restrict__ x, u16* __restrict__ xo,
    const float* __restrict__ Ws0_0, const float* __restrict__ Ws0_1,
    const float* __restrict__ Wn0_0, const float* __restrict__ Wn0_1,
    const float* __restrict__ Wp_0,  const float* __restrict__ Wp_1,
    const float* __restrict__ Ws1_0, const float* __restrict__ Ws1_1,
    const float* __restrict__ Wn1_0, const float* __restrict__ Wn1_1,
    const float* __restrict__ b0_0, const float* __restrict__ b0_1,
    const float* __restrict__ b1_0, const float* __restrict__ b1_1,
    const float* __restrict__ bp_0, const float* __restrict__ bp_1,
    u16* __restrict__ w, float* __restrict__ bsum0, float* __restrict__ bsum1,
    float* __restrict__ bpc)
{
    int bb = blockIdx.x;
    if (bb < 12500) {                         // x -> bf16 (NN*128/4 threads)
        int t = bb * 256 + threadIdx.x;
        const float4 v = reinterpret_cast<const float4*>(x)[t];
        ushort4 r; r.x = f2b(v.x); r.y = f2b(v.y); r.z = f2b(v.z); r.w = f2b(v.w);
        reinterpret_cast<ushort4*>(xo)[t] = r;
    } else {                                  // weight prep (418 blocks)
        int t = (bb - 12500) * 256 + threadIdx.x;
        if (t < 81920) {                      // five 128x128 transposes
            int m = t >> 14, u = t & 16383;
            int n = u >> 7, k = u & 127;
            float v;
            if (m == 0)      v = Ws0_0[k * 128 + n] + Ws0_1[k * 128 + n];
            else if (m == 1) v = Wn0_0[k * 128 + n];
            else if (m == 2) v = Wn0_1[k * 128 + n];
            else if (m == 3) v = Wp_0[k * 128 + n];
            else             v = Wp_1[k * 128 + n];
            w[t] = f2b(v);
        } else if (t < 106496) {              // three 64x128 transposed
            int u = t - 81920;
            int m = u >> 13; u &= 8191;
            int n = u >> 7, k = u & 127;
            float v;
            if (m == 0)      v = Ws1_0[k * 64 + n] + Ws1_1[k * 64 + n];
            else if (m == 1) v = Wn1_0[k * 64 + n];
            else             v = Wn1_1[k * 64 + n];
            w[t] = f2b(v);
        } else if (t < 106624) {
            int i = t - 106496; bsum0[i] = b0_0[i] + b0_1[i];
        } else if (t < 106688) {
            int i = t - 106624; bsum1[i] = b1_0[i] + b1_1[i];
        } else if (t < 106944) {
            int i = t - 106688; bpc[i] = (i < 128) ? bp_0[i] : bp_1[i - 128];
        }
    }
}

// ---------------- prefix scan ----------------
__global__ void scan_local(const int* __restrict__ deg0, const int* __restrict__ deg1,
                           int* __restrict__ offs0, int* __restrict__ offs1,
                           int* __restrict__ bsA, int* __restrict__ bsB)
{
    __shared__ int sm[1024];
    int rel = blockIdx.x >= 98;
    int blk = blockIdx.x - rel * 98;
    const int* in = rel ? deg1 : deg0;
    int* out = rel ? offs1 : offs0;
    int* bsum = rel ? bsB : bsA;
    int t = threadIdx.x;
    int i = blk * 1024 + t;
    int v = (i < NN) ? in[i] : 0;
    sm[t] = v;
    __syncthreads();
    for (int off = 1; off < 1024; off <<= 1) {
        int add = (t >= off) ? sm[t - off] : 0;
        __syncthreads();
        sm[t] += add;
        __syncthreads();
    }
    if (i < NN) out[i] = sm[t] - v;            // exclusive
    if (t == 1023) bsum[blk] = sm[1023];
}

__global__ void scan_bsums(int* __restrict__ bsA, int* __restrict__ bsB)
{
    __shared__ int sm[128];
    int* bsum = blockIdx.x ? bsB : bsA;
    int t = threadIdx.x;
    int v = (t < 98) ? bsum[t] : 0;
    sm[t] = v;
    __syncthreads();
    for (int off = 1; off < 128; off <<= 1) {
        int add = (t >= off) ? sm[t - off] : 0;
        __syncthreads();
        sm[t] += add;
        __syncthreads();
    }
    if (t < 98) bsum[t] = sm[t] - v;           // exclusive
}

__global__ void scan_add(int* __restrict__ offs0, int* __restrict__ offs1,
                         const int* __restrict__ bsA, const int* __restrict__ bsB,
                         int* __restrict__ cur0, int* __restrict__ cur1,
                         u32* __restrict__ csr0, u32* __restrict__ csr1)
{
    int rel = blockIdx.x >= 392;
    int i = (blockIdx.x - rel * 392) * 256 + threadIdx.x;
    int* offs = rel ? offs1 : offs0;
    int* cur = rel ? cur1 : cur0;
    const int* bsum = rel ? bsB : bsA;
    if (i < NN) {
        int v = offs[i] + bsum[i >> 10];
        offs[i] = v;
        cur[i] = v;
    }
    if (i == 0) offs[NN] = NE;
    if (blockIdx.x == 0 && threadIdx.x < 8) {  // pads for gather unroll-8 over-read
        csr0[NE + threadIdx.x] = 0;
        csr1[NE + threadIdx.x] = 0;
    }
}

// ---------------- CSR build, XCD-partitioned, co-resident grid (2048 blocks) ----------------
// Entry = (src << 15) | (top 15 bits of f32(ew), round-to-nearest); decode = as_float(E<<17).
__global__ __launch_bounds__(256) void build_csr_part(
    const int* __restrict__ src0, const int* __restrict__ dst0,
    const float* __restrict__ ew0,
    const int* __restrict__ src1, const int* __restrict__ dst1,
    const float* __restrict__ ew1,
    int* __restrict__ cur0, int* __restrict__ cur1,
    u32* __restrict__ csr0, u32* __restrict__ csr1)
{
    int part = blockIdx.x & 7;
    int sub = blockIdx.x >> 3;
    int rel = sub & 1;
    int chunk = sub >> 1;
    const int lo = part * PART, hi = lo + PART;
    const int* src = rel ? src1 : src0;
    const int* dst = rel ? dst1 : dst0;
    const float* ew = rel ? ew1 : ew0;
    int* cur = rel ? cur1 : cur0;
    u32* csr = rel ? csr1 : csr0;
    const int e0 = chunk * ECH;
    const int e1 = min(e0 + ECH, NE);
    for (int e = e0 + threadIdx.x; e < e1; e += 256) {
        int d = dst[e];
        if (d >= lo && d < hi) {
            int p = atomicAdd(&cur[d], 1);
            u32 q = (__float_as_uint(ew[e]) + 0x10000u) >> 17;
            csr[p] = ((u32)src[e] << 15) | q;
        }
    }
}

// ---------------- flat gather (mean or max), wave per node, unroll-8 ----------------
template<bool MAXAGG>
__global__ __launch_bounds__(256) void gather(
    const u16* __restrict__ F0, const u16* __restrict__ F1,
    const int* __restrict__ offs0, const u32* __restrict__ csr0, u16* __restrict__ o0,
    const int* __restrict__ offs1, const u32* __restrict__ csr1, u16* __restrict__ o1)
{
    int b = blockIdx.x;
    int rel = b >= 25000;
    const u16* F = rel ? F1 : F0;
    const int* offs = rel ? offs1 : offs0;
    const u32* csr = rel ? csr1 : csr0;
    u16* out = rel ? o1 : o0;
    int node = (b - rel * 25000) * 4 + (threadIdx.x >> 6);
    int lane2 = (threadIdx.x & 63) << 1;
    int beg = __builtin_amdgcn_readfirstlane(offs[node]);
    int end = __builtin_amdgcn_readfirstlane(offs[node + 1]);

    float a0 = 0.f, a1 = 0.f;
    for (int e = beg; e < end; e += 8) {
        u32 E[8], v[8];
#pragma unroll
        for (int i = 0; i < 8; ++i)
            E[i] = csr[e + i];
#pragma unroll
        for (int i = 0; i < 8; ++i)
            v[i] = *reinterpret_cast<const u32*>(F + ((size_t)(E[i] >> 15) << 7) + lane2);
#pragma unroll
        for (int i = 0; i < 8; ++i) {
            float wgt = (e + i < end) ? __uint_as_float(E[i] << 17) : 0.f;
            float f0 = __uint_as_float(v[i] << 16);
            float f1 = __uint_as_float(v[i] & 0xFFFF0000u);
            if (MAXAGG) { a0 = fmaxf(a0, f0 * wgt); a1 = fmaxf(a1, f1 * wgt); }
            else        { a0 = fmaf(f0, wgt, a0);   a1 = fmaf(f1, wgt, a1); }
        }
    }
    float s = MAXAGG ? 1.f : 1.f / fmaxf((float)(end - beg), 1.f);
    ushort2 r; r.x = f2b(a0 * s); r.y = f2b(a1 * s);
    *reinterpret_cast<ushort2*>(out + (size_t)node * 128 + lane2) = r;
}

// ---------------- register-B multi-pair MFMA GEMM (no LDS, no barriers) ----------------
// Per tile: issue ALL NPAIR*8 A-fragment loads into registers, then all MFMAs.
// __launch_bounds__(.,2) caps at 2 waves/EU -> 256 VGPR budget.
template<int NPAIR, int COLGROUPS, int WAVES, bool RELU, bool OUTF32, bool DUAL>
__global__ __launch_bounds__(WAVES * 64, 2) void gemm_reg(
    const u16* __restrict__ A0, const u16* __restrict__ A1, const u16* __restrict__ A2,
    const u16* __restrict__ BT, const float* __restrict__ bias,
    float* __restrict__ outF, u16* __restrict__ outB, u16* __restrict__ outB2)
{
    constexpr int NC = COLGROUPS * 32;
    constexpr int RT = WAVES / COLGROUPS;
    constexpr int OST = DUAL ? (NC / 2) : NC;
    constexpr int NTILES = NN / 32;
    const int w = threadIdx.x >> 6, l = threadIdx.x & 63;
    const int cg = w % COLGROUPS, rsub = w / COLGROUPS;
    const int l15 = l & 15, lk = (l >> 4) << 3, rq = (l >> 4) << 2;

    bf16x8 bfr[NPAIR][4][2];
#pragma unroll
    for (int p = 0; p < NPAIR; ++p)
#pragma unroll
        for (int ks = 0; ks < 4; ++ks)
#pragma unroll
            for (int cf = 0; cf < 2; ++cf) {
                int n = p * NC + cg * 32 + cf * 16 + l15;
                bfr[p][ks][cf] = *reinterpret_cast<const bf16x8*>(BT + (size_t)n * 128 + ks * 32 + lk);
            }

    const u16* As[3] = {A0, A1, A2};
    const float bv0 = bias[cg * 32 + l15];
    const float bv1 = bias[cg * 32 + 16 + l15];

    for (int tile = blockIdx.x * RT + rsub; tile < NTILES; tile += gridDim.x * RT) {
        const size_t rowbase = (size_t)tile * 32;

        bf16x8 af[NPAIR][4][2];
#pragma unroll
        for (int p = 0; p < NPAIR; ++p) {
            const u16* A = As[p] + rowbase * 128;
#pragma unroll
            for (int ks = 0; ks < 4; ++ks) {
                const int k0 = ks * 32 + lk;
                af[p][ks][0] = *reinterpret_cast<const bf16x8*>(A + (size_t)l15 * 128 + k0);
                af[p][ks][1] = *reinterpret_cast<const bf16x8*>(A + (size_t)(16 + l15) * 128 + k0);
            }
        }

        f32x4 acc[2][2];
#pragma unroll
        for (int rf = 0; rf < 2; ++rf)
#pragma unroll
            for (int cf = 0; cf < 2; ++cf)
                acc[rf][cf] = f32x4{0.f, 0.f, 0.f, 0.f};

#pragma unroll
        for (int p = 0; p < NPAIR; ++p)
#pragma unroll
            for (int ks = 0; ks < 4; ++ks) {
                acc[0][0] = __builtin_amdgcn_mfma_f32_16x16x32_bf16(af[p][ks][0], bfr[p][ks][0], acc[0][0], 0, 0, 0);
                acc[0][1] = __builtin_amdgcn_mfma_f32_16x16x32_bf16(af[p][ks][0], bfr[p][ks][1], acc[0][1], 0, 0, 0);
                acc[1][0] = __builtin_amdgcn_mfma_f32_16x16x32_bf16(af[p][ks][1], bfr[p][ks][0], acc[1][0], 0, 0, 0);
                acc[1][1] = __builtin_amdgcn_mfma_f32_16x16x32_bf16(af[p][ks][1], bfr[p][ks][1], acc[1][1], 0, 0, 0);
            }

        u16* ob = outB;
        if (DUAL && cg >= 4) ob = outB2;
        const int colbase = (DUAL ? (cg & 3) : cg) * 32;
#pragma unroll
        for (int cf = 0; cf < 2; ++cf) {
            const int col = colbase + cf * 16 + l15;
            const float bv = cf ? bv1 : bv0;
#pragma unroll
            for (int rf = 0; rf < 2; ++rf) {
#pragma unroll
                for (int j = 0; j < 4; ++j) {
                    const size_t row = rowbase + rf * 16 + rq + j;
                    float v = acc[rf][cf][j] + bv;
                    if (RELU) v = fmaxf(v, 0.f);
                    if (OUTF32) outF[row * OST + col] = v;
                    else        ob[row * OST + col] = f2b(v);
                }
            }
        }
    }
}

extern "C" void kernel_launch(void* const* d_in, const int* in_sizes, int n_in,
                              void* d_out, int out_size, void* d_ws, size_t ws_size,
                              hipStream_t stream)
{
    const float* x     = (const float*)d_in[0];
    const int*   src0  = (const int*)d_in[1];
    const int*   dst0  = (const int*)d_in[2];
    const float* ew0   = (const float*)d_in[3];
    const int*   src1  = (const int*)d_in[4];
    const int*   dst1  = (const int*)d_in[5];
    const float* ew1   = (const float*)d_in[6];
    const float* Ws0_0 = (const float*)d_in[7];
    const float* Wn0_0 = (const float*)d_in[8];
    const float* b0_0  = (const float*)d_in[9];
    const float* Wp_0  = (const float*)d_in[10];
    const float* bp_0  = (const float*)d_in[11];
    const float* Ws1_0 = (const float*)d_in[12];
    const float* Wn1_0 = (const float*)d_in[13];
    const float* b1_0  = (const float*)d_in[14];
    const float* Ws0_1 = (const float*)d_in[15];
    const float* Wn0_1 = (const float*)d_in[16];
    const float* b0_1  = (const float*)d_in[17];
    const float* Wp_1  = (const float*)d_in[18];
    const float* bp_1  = (const float*)d_in[19];
    const float* Ws1_1 = (const float*)d_in[20];
    const float* Wn1_1 = (const float*)d_in[21];
    const float* b1_1  = (const float*)d_in[22];

    char* ws = (char*)d_ws;
    u16*   x16   = (u16*)(ws + 0);            // x bf16; reused as hp0 later
    u16*   h16   = (u16*)(ws + 25600000);
    u16*   a0    = (u16*)(ws + 51200000);     // mean-agg r0; reused as max-agg r0
    u16*   a1    = (u16*)(ws + 76800000);     // mean-agg r1; reused as max-agg r1
    u16*   hp1   = (u16*)(ws + 102400000);
    u32*   csr0  = (u32*)(ws + 128000000);    // NE+8 packed entries
    u32*   csr1  = (u32*)(ws + 130400032);
    int*   offs0 = (int*)(ws + 132800064);
    int*   offs1 = (int*)(ws + 133200080);
    int*   cur0  = (int*)(ws + 133600096);
    int*   cur1  = (int*)(ws + 134000096);
    int*   deg0  = (int*)(ws + 134400096);
    int*   deg1  = (int*)(ws + 134800096);    // contiguous with deg0
    int*   bsA   = (int*)(ws + 135200096);
    int*   bsB   = (int*)(ws + 135200608);
    u16*   wts   = (u16*)(ws + 135201120);
    float* bsum0 = (float*)(ws + 135414112);
    float* bsum1 = (float*)(ws + 135414624);
    float* bpc   = (float*)(ws + 135415136);

    u16* hp0 = x16;                           // x16 dead after layer-0 GEMM

    hipMemsetAsync(deg0, 0, 800000, stream);
    deg_part<<<2048, 256, 0, stream>>>(dst0, dst1, deg0, deg1);
    fused_setup<<<12918, 256, 0, stream>>>(
        x, x16, Ws0_0, Ws0_1, Wn0_0, Wn0_1, Wp_0, Wp_1,
        Ws1_0, Ws1_1, Wn1_0, Wn1_1, b0_0, b0_1, b1_0, b1_1, bp_0, bp_1,
        wts, bsum0, bsum1, bpc);

    scan_local<<<196, 1024, 0, stream>>>(deg0, deg1, offs0, offs1, bsA, bsB);
    scan_bsums<<<2, 128, 0, stream>>>(bsA, bsB);
    scan_add<<<784, 256, 0, stream>>>(offs0, offs1, bsA, bsB, cur0, cur1, csr0, csr1);
    build_csr_part<<<2048, 256, 0, stream>>>(
        src0, dst0, ew0, src1, dst1, ew1, cur0, cur1, csr0, csr1);

    // ---- layer 0 ----
    gather<false><<<50000, 256, 0, stream>>>(
        x16, x16, offs0, csr0, a0, offs1, csr1, a1);
    gemm_reg<3, 4, 4, true, false, false><<<1024, 256, 0, stream>>>(
        x16, a0, a1, wts, bsum0, nullptr, h16, nullptr);

    // ---- layer 1 ----
    gemm_reg<1, 8, 8, true, false, true><<<512, 512, 0, stream>>>(
        h16, nullptr, nullptr, wts + 49152, bpc, nullptr, hp0, hp1);
    gather<true><<<50000, 256, 0, stream>>>(
        hp0, hp1, offs0, csr0, a0, offs1, csr1, a1);
    gemm_reg<3, 2, 4, false, true, false><<<782, 256, 0, stream>>>(
        h16, a0, a1, wts + 81920, bsum1, (float*)d_out, nullptr, nullptr);
}

// Round 18
// 362.265 us; speedup vs baseline: 1.0111x; 1.0111x over previous
//
#include <hip/hip_runtime.h>

typedef short bf16x8 __attribute__((ext_vector_type(8)));
typedef float f32x4 __attribute__((ext_vector_type(4)));
typedef float f32x2 __attribute__((ext_vector_type(2)));
typedef unsigned short u16;
typedef unsigned int u32;
typedef unsigned char u8;

#define NN 100000
#define NE 600000
#define PART 12500        // NN / 8
#define ECH 4688          // ceil(NE / 128)

__device__ __forceinline__ u16 f2b(float f) {
    u32 u = __float_as_uint(f);
    return (u16)((u + 0x7FFFu + ((u >> 16) & 1u)) >> 16);
}

// ---------------- XCD-partitioned degree count, standalone co-resident grid ----------------
// MUST be its own dispatch (r15: fusing with conv_x stream evicts counter lines, +37MB wb).
__global__ __launch_bounds__(256) void deg_part(
    const int* __restrict__ d0, const int* __restrict__ d1,
    int* __restrict__ g0, int* __restrict__ g1)
{
    int part = blockIdx.x & 7;
    int sub = blockIdx.x >> 3;                // 0..255
    int rel = sub & 1;
    int chunk = sub >> 1;                     // 0..127
    const int lo = part * PART, hi = lo + PART;
    const int* d = rel ? d1 : d0;
    int* g = rel ? g1 : g0;
    const int e0 = chunk * ECH;
    const int e1 = min(e0 + ECH, NE);
    for (int e = e0 + threadIdx.x; e < e1; e += 256) {
        int dd = d[e];
        if (dd >= lo && dd < hi) atomicAdd(&g[dd], 1);
    }
}

// ---------------- fused setup: x->bf16 + x->fp8 | weight prep ----------------
// x16: bf16 [NN][128] (MFMA A operand). x8: fp8 e4m3 [NN][128] (mean-gather table,
// 128B rows -> halves random-gather traffic; error softened by degree-averaging).
__global__ void fused_setup(
    const float* __restrict__ x, u16* __restrict__ xo, u8* __restrict__ x8,
    const float* __restrict__ Ws0_0, const float* __restrict__ Ws0_1,
    const float* __restrict__ Wn0_0, const float* __restrict__ Wn0_1,
    const float* __restrict__ Wp_0,  const float* __restrict__ Wp_1,
    const float* __restrict__ Ws1_0, const float* __restrict__ Ws1_1,
    const float* __restrict__ Wn1_0, const float* __restrict__ Wn1_1,
    const float* __restrict__ b0_0, const float* __restrict__ b0_1,
    const float* __restrict__ b1_0, const float* __restrict__ b1_1,
    const float* __restrict__ bp_0, const float* __restrict__ bp_1,
    u16* __restrict__ w, float* __restrict__ bsum0, float* __restrict__ bsum1,
    float* __restrict__ bpc)
{
    int bb = blockIdx.x;
    if (bb < 12500) {                         // x conversions (NN*128/4 threads)
        int t = bb * 256 + threadIdx.x;
        const float4 v = reinterpret_cast<const float4*>(x)[t];
        ushort4 r; r.x = f2b(v.x); r.y = f2b(v.y); r.z = f2b(v.z); r.w = f2b(v.w);
        reinterpret_cast<ushort4*>(xo)[t] = r;
        u32 p = __builtin_amdgcn_cvt_pk_fp8_f32(v.x, v.y, 0, false);
        p = __builtin_amdgcn_cvt_pk_fp8_f32(v.z, v.w, p, true);
        reinterpret_cast<u32*>(x8)[t] = p;
    } else {                                  // weight prep (418 blocks)
        int t = (bb - 12500) * 256 + threadIdx.x;
        if (t < 81920) {                      // five 128x128 transposes
            int m = t >> 14, u = t & 16383;
            int n = u >> 7, k = u & 127;
            float v;
            if (m == 0)      v = Ws0_0[k * 128 + n] + Ws0_1[k * 128 + n];
            else if (m == 1) v = Wn0_0[k * 128 + n];
            else if (m == 2) v = Wn0_1[k * 128 + n];
            else if (m == 3) v = Wp_0[k * 128 + n];
            else             v = Wp_1[k * 128 + n];
            w[t] = f2b(v);
        } else if (t < 106496) {              // three 64x128 transposed
            int u = t - 81920;
            int m = u >> 13; u &= 8191;
            int n = u >> 7, k = u & 127;
            float v;
            if (m == 0)      v = Ws1_0[k * 64 + n] + Ws1_1[k * 64 + n];
            else if (m == 1) v = Wn1_0[k * 64 + n];
            else             v = Wn1_1[k * 64 + n];
            w[t] = f2b(v);
        } else if (t < 106624) {
            int i = t - 106496; bsum0[i] = b0_0[i] + b0_1[i];
        } else if (t < 106688) {
            int i = t - 106624; bsum1[i] = b1_0[i] + b1_1[i];
        } else if (t < 106944) {
            int i = t - 106688; bpc[i] = (i < 128) ? bp_0[i] : bp_1[i - 128];
        }
    }
}

// ---------------- prefix scan ----------------
__global__ void scan_local(const int* __restrict__ deg0, const int* __restrict__ deg1,
                           int* __restrict__ offs0, int* __restrict__ offs1,
                           int* __restrict__ bsA, int* __restrict__ bsB)
{
    __shared__ int sm[1024];
    int rel = blockIdx.x >= 98;
    int blk = blockIdx.x - rel * 98;
    const int* in = rel ? deg1 : deg0;
    int* out = rel ? offs1 : offs0;
    int* bsum = rel ? bsB : bsA;
    int t = threadIdx.x;
    int i = blk * 1024 + t;
    int v = (i < NN) ? in[i] : 0;
    sm[t] = v;
    __syncthreads();
    for (int off = 1; off < 1024; off <<= 1) {
        int add = (t >= off) ? sm[t - off] : 0;
        __syncthreads();
        sm[t] += add;
        __syncthreads();
    }
    if (i < NN) out[i] = sm[t] - v;            // exclusive
    if (t == 1023) bsum[blk] = sm[1023];
}

__global__ void scan_bsums(int* __restrict__ bsA, int* __restrict__ bsB)
{
    __shared__ int sm[128];
    int* bsum = blockIdx.x ? bsB : bsA;
    int t = threadIdx.x;
    int v = (t < 98) ? bsum[t] : 0;
    sm[t] = v;
    __syncthreads();
    for (int off = 1; off < 128; off <<= 1) {
        int add = (t >= off) ? sm[t - off] : 0;
        __syncthreads();
        sm[t] += add;
        __syncthreads();
    }
    if (t < 98) bsum[t] = sm[t] - v;           // exclusive
}

__global__ void scan_add(int* __restrict__ offs0, int* __restrict__ offs1,
                         const int* __restrict__ bsA, const int* __restrict__ bsB,
                         int* __restrict__ cur0, int* __restrict__ cur1,
                         u32* __restrict__ csr0, u32* __restrict__ csr1)
{
    int rel = blockIdx.x >= 392;
    int i = (blockIdx.x - rel * 392) * 256 + threadIdx.x;
    int* offs = rel ? offs1 : offs0;
    int* cur = rel ? cur1 : cur0;
    const int* bsum = rel ? bsB : bsA;
    if (i < NN) {
        int v = offs[i] + bsum[i >> 10];
        offs[i] = v;
        cur[i] = v;
    }
    if (i == 0) offs[NN] = NE;
    if (blockIdx.x == 0 && threadIdx.x < 8) {  // pads for gather unroll-8 over-read
        csr0[NE + threadIdx.x] = 0;
        csr1[NE + threadIdx.x] = 0;
    }
}

// ---------------- CSR build, XCD-partitioned, co-resident grid (2048 blocks) ----------------
// Entry = (src << 15) | (top 15 bits of f32(ew), round-to-nearest); decode = as_float(E<<17).
__global__ __launch_bounds__(256) void build_csr_part(
    const int* __restrict__ src0, const int* __restrict__ dst0,
    const float* __restrict__ ew0,
    const int* __restrict__ src1, const int* __restrict__ dst1,
    const float* __restrict__ ew1,
    int* __restrict__ cur0, int* __restrict__ cur1,
    u32* __restrict__ csr0, u32* __restrict__ csr1)
{
    int part = blockIdx.x & 7;
    int sub = blockIdx.x >> 3;
    int rel = sub & 1;
    int chunk = sub >> 1;
    const int lo = part * PART, hi = lo + PART;
    const int* src = rel ? src1 : src0;
    const int* dst = rel ? dst1 : dst0;
    const float* ew = rel ? ew1 : ew0;
    int* cur = rel ? cur1 : cur0;
    u32* csr = rel ? csr1 : csr0;
    const int e0 = chunk * ECH;
    const int e1 = min(e0 + ECH, NE);
    for (int e = e0 + threadIdx.x; e < e1; e += 256) {
        int d = dst[e];
        if (d >= lo && d < hi) {
            int p = atomicAdd(&cur[d], 1);
            u32 q = (__float_as_uint(ew[e]) + 0x10000u) >> 17;
            csr[p] = ((u32)src[e] << 15) | q;
        }
    }
}

// ---------------- flat gather, wave per node, unroll-8 ----------------
// FP8: table rows 128B fp8 e4m3 (mean path); else bf16 256B rows (max path).
template<bool MAXAGG, bool FP8>
__global__ __launch_bounds__(256) void gather(
    const u8* __restrict__ F0, const u8* __restrict__ F1,
    const int* __restrict__ offs0, const u32* __restrict__ csr0, u16* __restrict__ o0,
    const int* __restrict__ offs1, const u32* __restrict__ csr1, u16* __restrict__ o1)
{
    int b = blockIdx.x;
    int rel = b >= 25000;
    const u8* F = rel ? F1 : F0;
    const int* offs = rel ? offs1 : offs0;
    const u32* csr = rel ? csr1 : csr0;
    u16* out = rel ? o1 : o0;
    int node = (b - rel * 25000) * 4 + (threadIdx.x >> 6);
    int lane2 = (threadIdx.x & 63) << 1;       // 2 features per lane
    int beg = __builtin_amdgcn_readfirstlane(offs[node]);
    int end = __builtin_amdgcn_readfirstlane(offs[node + 1]);

    float a0 = 0.f, a1 = 0.f;
    for (int e = beg; e < end; e += 8) {
        u32 E[8], v[8];
#pragma unroll
        for (int i = 0; i < 8; ++i)
            E[i] = csr[e + i];
#pragma unroll
        for (int i = 0; i < 8; ++i) {
            if (FP8)
                v[i] = *reinterpret_cast<const u16*>(F + ((size_t)(E[i] >> 15) << 7) + lane2);
            else
                v[i] = *reinterpret_cast<const u32*>(F + ((size_t)(E[i] >> 15) << 8) + (lane2 << 1));
        }
#pragma unroll
        for (int i = 0; i < 8; ++i) {
            float wgt = (e + i < end) ? __uint_as_float(E[i] << 17) : 0.f;
            float f0, f1;
            if (FP8) {
                f32x2 d = __builtin_amdgcn_cvt_pk_f32_fp8(v[i], false);
                f0 = d.x; f1 = d.y;
            } else {
                f0 = __uint_as_float(v[i] << 16);
                f1 = __uint_as_float(v[i] & 0xFFFF0000u);
            }
            if (MAXAGG) { a0 = fmaxf(a0, f0 * wgt); a1 = fmaxf(a1, f1 * wgt); }
            else        { a0 = fmaf(f0, wgt, a0);   a1 = fmaf(f1, wgt, a1); }
        }
    }
    float s = MAXAGG ? 1.f : 1.f / fmaxf((float)(end - beg), 1.f);
    ushort2 r; r.x = f2b(a0 * s); r.y = f2b(a1 * s);
    *reinterpret_cast<ushort2*>(out + (size_t)node * 128 + lane2) = r;
}

// ---------------- register-B multi-pair MFMA GEMM (no LDS, no barriers) ----------------
template<int NPAIR, int COLGROUPS, int WAVES, bool RELU, bool OUTF32, bool DUAL>
__global__ __launch_bounds__(WAVES * 64, 2) void gemm_reg(
    const u16* __restrict__ A0, const u16* __restrict__ A1, const u16* __restrict__ A2,
    const u16* __restrict__ BT, const float* __restrict__ bias,
    float* __restrict__ outF, u16* __restrict__ outB, u16* __restrict__ outB2)
{
    constexpr int NC = COLGROUPS * 32;
    constexpr int RT = WAVES / COLGROUPS;
    constexpr int OST = DUAL ? (NC / 2) : NC;
    constexpr int NTILES = NN / 32;
    const int w = threadIdx.x >> 6, l = threadIdx.x & 63;
    const int cg = w % COLGROUPS, rsub = w / COLGROUPS;
    const int l15 = l & 15, lk = (l >> 4) << 3, rq = (l >> 4) << 2;

    bf16x8 bfr[NPAIR][4][2];
#pragma unroll
    for (int p = 0; p < NPAIR; ++p)
#pragma unroll
        for (int ks = 0; ks < 4; ++ks)
#pragma unroll
            for (int cf = 0; cf < 2; ++cf) {
                int n = p * NC + cg * 32 + cf * 16 + l15;
                bfr[p][ks][cf] = *reinterpret_cast<const bf16x8*>(BT + (size_t)n * 128 + ks * 32 + lk);
            }

    const u16* As[3] = {A0, A1, A2};
    const float bv0 = bias[cg * 32 + l15];
    const float bv1 = bias[cg * 32 + 16 + l15];

    for (int tile = blockIdx.x * RT + rsub; tile < NTILES; tile += gridDim.x * RT) {
        const size_t rowbase = (size_t)tile * 32;

        bf16x8 af[NPAIR][4][2];
#pragma unroll
        for (int p = 0; p < NPAIR; ++p) {
            const u16* A = As[p] + rowbase * 128;
#pragma unroll
            for (int ks = 0; ks < 4; ++ks) {
                const int k0 = ks * 32 + lk;
                af[p][ks][0] = *reinterpret_cast<const bf16x8*>(A + (size_t)l15 * 128 + k0);
                af[p][ks][1] = *reinterpret_cast<const bf16x8*>(A + (size_t)(16 + l15) * 128 + k0);
            }
        }

        f32x4 acc[2][2];
#pragma unroll
        for (int rf = 0; rf < 2; ++rf)
#pragma unroll
            for (int cf = 0; cf < 2; ++cf)
                acc[rf][cf] = f32x4{0.f, 0.f, 0.f, 0.f};

#pragma unroll
        for (int p = 0; p < NPAIR; ++p)
#pragma unroll
            for (int ks = 0; ks < 4; ++ks) {
                acc[0][0] = __builtin_amdgcn_mfma_f32_16x16x32_bf16(af[p][ks][0], bfr[p][ks][0], acc[0][0], 0, 0, 0);
                acc[0][1] = __builtin_amdgcn_mfma_f32_16x16x32_bf16(af[p][ks][0], bfr[p][ks][1], acc[0][1], 0, 0, 0);
                acc[1][0] = __builtin_amdgcn_mfma_f32_16x16x32_bf16(af[p][ks][1], bfr[p][ks][0], acc[1][0], 0, 0, 0);
                acc[1][1] = __builtin_amdgcn_mfma_f32_16x16x32_bf16(af[p][ks][1], bfr[p][ks][1], acc[1][1], 0, 0, 0);
            }

        u16* ob = outB;
        if (DUAL && cg >= 4) ob = outB2;
        const int colbase = (DUAL ? (cg & 3) : cg) * 32;
#pragma unroll
        for (int cf = 0; cf < 2; ++cf) {
            const int col = colbase + cf * 16 + l15;
            const float bv = cf ? bv1 : bv0;
#pragma unroll
            for (int rf = 0; rf < 2; ++rf) {
#pragma unroll
                for (int j = 0; j < 4; ++j) {
                    const size_t row = rowbase + rf * 16 + rq + j;
                    float v = acc[rf][cf][j] + bv;
                    if (RELU) v = fmaxf(v, 0.f);
                    if (OUTF32) outF[row * OST + col] = v;
                    else        ob[row * OST + col] = f2b(v);
                }
            }
        }
    }
}

extern "C" void kernel_launch(void* const* d_in, const int* in_sizes, int n_in,
                              void* d_out, int out_size, void* d_ws, size_t ws_size,
                              hipStream_t stream)
{
    const float* x     = (const float*)d_in[0];
    const int*   src0  = (const int*)d_in[1];
    const int*   dst0  = (const int*)d_in[2];
    const float* ew0   = (const float*)d_in[3];
    const int*   src1  = (const int*)d_in[4];
    const int*   dst1  = (const int*)d_in[5];
    const float* ew1   = (const float*)d_in[6];
    const float* Ws0_0 = (const float*)d_in[7];
    const float* Wn0_0 = (const float*)d_in[8];
    const float* b0_0  = (const float*)d_in[9];
    const float* Wp_0  = (const float*)d_in[10];
    const float* bp_0  = (const float*)d_in[11];
    const float* Ws1_0 = (const float*)d_in[12];
    const float* Wn1_0 = (const float*)d_in[13];
    const float* b1_0  = (const float*)d_in[14];
    const float* Ws0_1 = (const float*)d_in[15];
    const float* Wn0_1 = (const float*)d_in[16];
    const float* b0_1  = (const float*)d_in[17];
    const float* Wp_1  = (const float*)d_in[18];
    const float* bp_1  = (const float*)d_in[19];
    const float* Ws1_1 = (const float*)d_in[20];
    const float* Wn1_1 = (const float*)d_in[21];
    const float* b1_1  = (const float*)d_in[22];

    char* ws = (char*)d_ws;
    u16*   x16   = (u16*)(ws + 0);            // x bf16; reused as hp0 (bf16) later
    u16*   h16   = (u16*)(ws + 25600000);
    u16*   a0    = (u16*)(ws + 51200000);     // mean-agg r0; reused as max-agg r0
    u16*   a1    = (u16*)(ws + 76800000);     // mean-agg r1; reused as max-agg r1
    u16*   hp1   = (u16*)(ws + 102400000);    // hp r1 bf16
    u32*   csr0  = (u32*)(ws + 128000000);    // NE+8 packed entries
    u32*   csr1  = (u32*)(ws + 130400032);
    int*   offs0 = (int*)(ws + 132800064);
    int*   offs1 = (int*)(ws + 133200080);
    int*   cur0  = (int*)(ws + 133600096);
    int*   cur1  = (int*)(ws + 134000096);
    int*   deg0  = (int*)(ws + 134400096);
    int*   deg1  = (int*)(ws + 134800096);    // contiguous with deg0
    int*   bsA   = (int*)(ws + 135200096);
    int*   bsB   = (int*)(ws + 135200608);
    u16*   wts   = (u16*)(ws + 135201120);
    float* bsum0 = (float*)(ws + 135414112);
    float* bsum1 = (float*)(ws + 135414624);
    float* bpc   = (float*)(ws + 135415136);
    u8*    x8    = (u8*)(ws + 136000000);     // x fp8 table (12.8MB)

    u16* hp0 = x16;                           // x16 dead after layer-0 GEMM

    hipMemsetAsync(deg0, 0, 800000, stream);
    deg_part<<<2048, 256, 0, stream>>>(dst0, dst1, deg0, deg1);
    fused_setup<<<12918, 256, 0, stream>>>(
        x, x16, x8, Ws0_0, Ws0_1, Wn0_0, Wn0_1, Wp_0, Wp_1,
        Ws1_0, Ws1_1, Wn1_0, Wn1_1, b0_0, b0_1, b1_0, b1_1, bp_0, bp_1,
        wts, bsum0, bsum1, bpc);

    scan_local<<<196, 1024, 0, stream>>>(deg0, deg1, offs0, offs1, bsA, bsB);
    scan_bsums<<<2, 128, 0, stream>>>(bsA, bsB);
    scan_add<<<784, 256, 0, stream>>>(offs0, offs1, bsA, bsB, cur0, cur1, csr0, csr1);
    build_csr_part<<<2048, 256, 0, stream>>>(
        src0, dst0, ew0, src1, dst1, ew1, cur0, cur1, csr0, csr1);

    // ---- layer 0: mean gather over fp8 x-table ----
    gather<false, true><<<50000, 256, 0, stream>>>(
        x8, x8, offs0, csr0, a0, offs1, csr1, a1);
    gemm_reg<3, 4, 4, true, false, false><<<1024, 256, 0, stream>>>(
        x16, a0, a1, wts, bsum0, nullptr, h16, nullptr);

    // ---- layer 1: dual Wp GEMM writes bf16 hp; max gather over bf16 ----
    gemm_reg<1, 8, 8, true, false, true><<<512, 512, 0, stream>>>(
        h16, nullptr, nullptr, wts + 49152, bpc, nullptr, hp0, hp1);
    gather<true, false><<<50000, 256, 0, stream>>>(
        (const u8*)hp0, (const u8*)hp1, offs0, csr0, a0, offs1, csr1, a1);
    gemm_reg<3, 2, 4, false, true, false><<<782, 256, 0, stream>>>(
        h16, a0, a1, wts + 81920, bsum1, (float*)d_out, nullptr, nullptr);
}

// Round 19
// 328.214 us; speedup vs baseline: 1.1160x; 1.1037x over previous
//
#include <hip/hip_runtime.h>

typedef short bf16x8 __attribute__((ext_vector_type(8)));
typedef float f32x4 __attribute__((ext_vector_type(4)));
typedef float f32x2 __attribute__((ext_vector_type(2)));
typedef unsigned short u16;
typedef unsigned int u32;
typedef unsigned char u8;

#define NN 100000
#define NE 600000
#define PART 12500        // NN / 8
#define ECH 4688          // ceil(NE / 128)

__device__ __forceinline__ u16 f2b(float f) {
    u32 u = __float_as_uint(f);
    return (u16)((u + 0x7FFFu + ((u >> 16) & 1u)) >> 16);
}

// ---------------- XCD-partitioned degree count, standalone co-resident grid ----------------
__global__ __launch_bounds__(256) void deg_part(
    const int* __restrict__ d0, const int* __restrict__ d1,
    int* __restrict__ g0, int* __restrict__ g1)
{
    int part = blockIdx.x & 7;
    int sub = blockIdx.x >> 3;                // 0..255
    int rel = sub & 1;
    int chunk = sub >> 1;                     // 0..127
    const int lo = part * PART, hi = lo + PART;
    const int* d = rel ? d1 : d0;
    int* g = rel ? g1 : g0;
    const int e0 = chunk * ECH;
    const int e1 = min(e0 + ECH, NE);
    for (int e = e0 + threadIdx.x; e < e1; e += 256) {
        int dd = d[e];
        if (dd >= lo && dd < hi) atomicAdd(&g[dd], 1);
    }
}

// ---------------- fused setup: x->bf16 + x->fp8 | weight prep ----------------
__global__ void fused_setup(
    const float* __restrict__ x, u16* __restrict__ xo, u8* __restrict__ x8,
    const float* __restrict__ Ws0_0, const float* __restrict__ Ws0_1,
    const float* __restrict__ Wn0_0, const float* __restrict__ Wn0_1,
    const float* __restrict__ Wp_0,  const float* __restrict__ Wp_1,
    const float* __restrict__ Ws1_0, const float* __restrict__ Ws1_1,
    const float* __restrict__ Wn1_0, const float* __restrict__ Wn1_1,
    const float* __restrict__ b0_0, const float* __restrict__ b0_1,
    const float* __restrict__ b1_0, const float* __restrict__ b1_1,
    const float* __restrict__ bp_0, const float* __restrict__ bp_1,
    u16* __restrict__ w, float* __restrict__ bsum0, float* __restrict__ bsum1,
    float* __restrict__ bpc)
{
    int bb = blockIdx.x;
    if (bb < 12500) {                         // x conversions (NN*128/4 threads)
        int t = bb * 256 + threadIdx.x;
        const float4 v = reinterpret_cast<const float4*>(x)[t];
        ushort4 r; r.x = f2b(v.x); r.y = f2b(v.y); r.z = f2b(v.z); r.w = f2b(v.w);
        reinterpret_cast<ushort4*>(xo)[t] = r;
        u32 p = __builtin_amdgcn_cvt_pk_fp8_f32(v.x, v.y, 0, false);
        p = __builtin_amdgcn_cvt_pk_fp8_f32(v.z, v.w, p, true);
        reinterpret_cast<u32*>(x8)[t] = p;
    } else {                                  // weight prep (418 blocks)
        int t = (bb - 12500) * 256 + threadIdx.x;
        if (t < 81920) {                      // five 128x128 transposes
            int m = t >> 14, u = t & 16383;
            int n = u >> 7, k = u & 127;
            float v;
            if (m == 0)      v = Ws0_0[k * 128 + n] + Ws0_1[k * 128 + n];
            else if (m == 1) v = Wn0_0[k * 128 + n];
            else if (m == 2) v = Wn0_1[k * 128 + n];
            else if (m == 3) v = Wp_0[k * 128 + n];
            else             v = Wp_1[k * 128 + n];
            w[t] = f2b(v);
        } else if (t < 106496) {              // three 64x128 transposed
            int u = t - 81920;
            int m = u >> 13; u &= 8191;
            int n = u >> 7, k = u & 127;
            float v;
            if (m == 0)      v = Ws1_0[k * 64 + n] + Ws1_1[k * 64 + n];
            else if (m == 1) v = Wn1_0[k * 64 + n];
            else             v = Wn1_1[k * 64 + n];
            w[t] = f2b(v);
        } else if (t < 106624) {
            int i = t - 106496; bsum0[i] = b0_0[i] + b0_1[i];
        } else if (t < 106688) {
            int i = t - 106624; bsum1[i] = b1_0[i] + b1_1[i];
        } else if (t < 106944) {
            int i = t - 106688; bpc[i] = (i < 128) ? bp_0[i] : bp_1[i - 128];
        }
    }
}

// ---------------- prefix scan ----------------
__global__ void scan_local(const int* __restrict__ deg0, const int* __restrict__ deg1,
                           int* __restrict__ offs0, int* __restrict__ offs1,
                           int* __restrict__ bsA, int* __restrict__ bsB)
{
    __shared__ int sm[1024];
    int rel = blockIdx.x >= 98;
    int blk = blockIdx.x - rel * 98;
    const int* in = rel ? deg1 : deg0;
    int* out = rel ? offs1 : offs0;
    int* bsum = rel ? bsB : bsA;
    int t = threadIdx.x;
    int i = blk * 1024 + t;
    int v = (i < NN) ? in[i] : 0;
    sm[t] = v;
    __syncthreads();
    for (int off = 1; off < 1024; off <<= 1) {
        int add = (t >= off) ? sm[t - off] : 0;
        __syncthreads();
        sm[t] += add;
        __syncthreads();
    }
    if (i < NN) out[i] = sm[t] - v;            // exclusive
    if (t == 1023) bsum[blk] = sm[1023];
}

__global__ void scan_bsums(int* __restrict__ bsA, int* __restrict__ bsB)
{
    __shared__ int sm[128];
    int* bsum = blockIdx.x ? bsB : bsA;
    int t = threadIdx.x;
    int v = (t < 98) ? bsum[t] : 0;
    sm[t] = v;
    __syncthreads();
    for (int off = 1; off < 128; off <<= 1) {
        int add = (t >= off) ? sm[t - off] : 0;
        __syncthreads();
        sm[t] += add;
        __syncthreads();
    }
    if (t < 98) bsum[t] = sm[t] - v;           // exclusive
}

__global__ void scan_add(int* __restrict__ offs0, int* __restrict__ offs1,
                         const int* __restrict__ bsA, const int* __restrict__ bsB,
                         int* __restrict__ cur0, int* __restrict__ cur1,
                         u32* __restrict__ csr0, u32* __restrict__ csr1)
{
    int rel = blockIdx.x >= 392;
    int i = (blockIdx.x - rel * 392) * 256 + threadIdx.x;
    int* offs = rel ? offs1 : offs0;
    int* cur = rel ? cur1 : cur0;
    const int* bsum = rel ? bsB : bsA;
    if (i < NN) {
        int v = offs[i] + bsum[i >> 10];
        offs[i] = v;
        cur[i] = v;
    }
    if (i == 0) offs[NN] = NE;
    if (blockIdx.x == 0 && threadIdx.x < 8) {  // pads for gather unroll-8 over-read
        csr0[NE + threadIdx.x] = 0;
        csr1[NE + threadIdx.x] = 0;
    }
}

// ---------------- CSR build, XCD-partitioned, co-resident grid (2048 blocks) ----------------
// Entry = (src << 15) | (top 15 bits of f32(ew), round-to-nearest); decode = as_float(E<<17).
__global__ __launch_bounds__(256) void build_csr_part(
    const int* __restrict__ src0, const int* __restrict__ dst0,
    const float* __restrict__ ew0,
    const int* __restrict__ src1, const int* __restrict__ dst1,
    const float* __restrict__ ew1,
    int* __restrict__ cur0, int* __restrict__ cur1,
    u32* __restrict__ csr0, u32* __restrict__ csr1)
{
    int part = blockIdx.x & 7;
    int sub = blockIdx.x >> 3;
    int rel = sub & 1;
    int chunk = sub >> 1;
    const int lo = part * PART, hi = lo + PART;
    const int* src = rel ? src1 : src0;
    const int* dst = rel ? dst1 : dst0;
    const float* ew = rel ? ew1 : ew0;
    int* cur = rel ? cur1 : cur0;
    u32* csr = rel ? csr1 : csr0;
    const int e0 = chunk * ECH;
    const int e1 = min(e0 + ECH, NE);
    for (int e = e0 + threadIdx.x; e < e1; e += 256) {
        int d = dst[e];
        if (d >= lo && d < hi) {
            int p = atomicAdd(&cur[d], 1);
            u32 q = (__float_as_uint(ew[e]) + 0x10000u) >> 17;
            csr[p] = ((u32)src[e] << 15) | q;
        }
    }
}

// ---------------- flat gather, wave per node, unroll-8 ----------------
// FP8: table rows 128B fp8 e4m3 (mean path); else bf16 256B rows (max path).
template<bool MAXAGG, bool FP8>
__global__ __launch_bounds__(256) void gather(
    const u8* __restrict__ F0, const u8* __restrict__ F1,
    const int* __restrict__ offs0, const u32* __restrict__ csr0, u16* __restrict__ o0,
    const int* __restrict__ offs1, const u32* __restrict__ csr1, u16* __restrict__ o1)
{
    int b = blockIdx.x;
    int rel = b >= 25000;
    const u8* F = rel ? F1 : F0;
    const int* offs = rel ? offs1 : offs0;
    const u32* csr = rel ? csr1 : csr0;
    u16* out = rel ? o1 : o0;
    int node = (b - rel * 25000) * 4 + (threadIdx.x >> 6);
    int lane2 = (threadIdx.x & 63) << 1;       // 2 features per lane
    int beg = __builtin_amdgcn_readfirstlane(offs[node]);
    int end = __builtin_amdgcn_readfirstlane(offs[node + 1]);

    float a0 = 0.f, a1 = 0.f;
    for (int e = beg; e < end; e += 8) {
        u32 E[8], v[8];
#pragma unroll
        for (int i = 0; i < 8; ++i)
            E[i] = csr[e + i];
#pragma unroll
        for (int i = 0; i < 8; ++i) {
            if (FP8)
                v[i] = *reinterpret_cast<const u16*>(F + ((size_t)(E[i] >> 15) << 7) + lane2);
            else
                v[i] = *reinterpret_cast<const u32*>(F + ((size_t)(E[i] >> 15) << 8) + (lane2 << 1));
        }
#pragma unroll
        for (int i = 0; i < 8; ++i) {
            float wgt = (e + i < end) ? __uint_as_float(E[i] << 17) : 0.f;
            float f0, f1;
            if (FP8) {
                f32x2 d = __builtin_amdgcn_cvt_pk_f32_fp8(v[i], false);
                f0 = d.x; f1 = d.y;
            } else {
                f0 = __uint_as_float(v[i] << 16);
                f1 = __uint_as_float(v[i] & 0xFFFF0000u);
            }
            if (MAXAGG) { a0 = fmaxf(a0, f0 * wgt); a1 = fmaxf(a1, f1 * wgt); }
            else        { a0 = fmaf(f0, wgt, a0);   a1 = fmaf(f1, wgt, a1); }
        }
    }
    float s = MAXAGG ? 1.f : 1.f / fmaxf((float)(end - beg), 1.f);
    ushort2 r; r.x = f2b(a0 * s); r.y = f2b(a1 * s);
    *reinterpret_cast<ushort2*>(out + (size_t)node * 128 + lane2) = r;
}

// ---------------- LDS-staged double-buffered MFMA GEMM ----------------
// A tiles (32 rows x 128 cols per operand) staged via reg->LDS with async split:
// issue next-tile global loads BEFORE compute, ds_write AFTER compute (T14).
// XOR swizzle byte ^= (row&7)<<4: conflict-free ds_write (linear slots) and
// ds_read_b128 (16 rows strided 256B -> 8-way spread -> 2-way = free).
// Block: WAVES waves, all on ONE tile; wave w owns 32-col group cg=w%COLGROUPS.
template<int NPAIR, int COLGROUPS, int WAVES, bool RELU, bool DUAL>
__global__ __launch_bounds__(WAVES * 64) void gemm_lds(
    const u16* __restrict__ A0, const u16* __restrict__ A1, const u16* __restrict__ A2,
    const u16* __restrict__ BT, const float* __restrict__ bias,
    u16* __restrict__ outB, u16* __restrict__ outB2)
{
    constexpr int NC = COLGROUPS * 32;
    constexpr int OST = DUAL ? (NC / 2) : NC;
    constexpr int NTILES = NN / 32;
    constexpr int THREADS = WAVES * 64;
    constexpr int NLOAD = NPAIR * 512 / THREADS;   // 16B slots per thread per tile
    __shared__ char lds[2 * NPAIR * 8192];

    const int t = threadIdx.x;
    const int w = t >> 6, l = t & 63;
    const int cg = w % COLGROUPS;
    const int l15 = l & 15, lk = (l >> 4) << 3, rq = (l >> 4) << 2;

    const u16* As[3] = {A0, A1, A2};

    // staging slot metadata (p, s compile-time-foldable per unrolled j)
    int goff[NLOAD], loff[NLOAD];
#pragma unroll
    for (int j = 0; j < NLOAD; ++j) {
        const int p = (j * THREADS) >> 9;               // operand (compile-time)
        const int s = ((j * THREADS) & 511) + t;        // slot in [0,512)
        goff[j] = s * 8;                                // u16 offset within operand tile
        loff[j] = p * 8192 + ((s * 16) ^ (((s >> 4) & 7) << 4));
    }

    // B fragments in registers (wave's 32-col slice)
    bf16x8 bfr[NPAIR][4][2];
#pragma unroll
    for (int p = 0; p < NPAIR; ++p)
#pragma unroll
        for (int ks = 0; ks < 4; ++ks)
#pragma unroll
            for (int cf = 0; cf < 2; ++cf) {
                int n = p * NC + cg * 32 + cf * 16 + l15;
                bfr[p][ks][cf] = *reinterpret_cast<const bf16x8*>(BT + (size_t)n * 128 + ks * 32 + lk);
            }
    const float bv0 = bias[cg * 32 + l15];
    const float bv1 = bias[cg * 32 + 16 + l15];

    u16* ob = outB;
    if (DUAL && cg >= 4) ob = outB2;
    const int colbase = (DUAL ? (cg & 3) : cg) * 32;

    uint4 v[NLOAD];
    int tile = blockIdx.x;
    // prologue: stage tile0 into buf0
#pragma unroll
    for (int j = 0; j < NLOAD; ++j) {
        const int p = (j * THREADS) >> 9;
        v[j] = *reinterpret_cast<const uint4*>(As[p] + (size_t)tile * 4096 + goff[j]);
    }
#pragma unroll
    for (int j = 0; j < NLOAD; ++j)
        *reinterpret_cast<uint4*>(&lds[loff[j]]) = v[j];
    __syncthreads();

    int buf = 0;
    while (tile < NTILES) {
        const int nxt = tile + (int)gridDim.x;
        if (nxt < NTILES) {                    // issue next tile's loads (async)
#pragma unroll
            for (int j = 0; j < NLOAD; ++j) {
                const int p = (j * THREADS) >> 9;
                v[j] = *reinterpret_cast<const uint4*>(As[p] + (size_t)nxt * 4096 + goff[j]);
            }
        }

        // compute current tile from LDS
        const int bb = buf * NPAIR * 8192;
        f32x4 acc[2][2];
#pragma unroll
        for (int rf = 0; rf < 2; ++rf)
#pragma unroll
            for (int cf = 0; cf < 2; ++cf)
                acc[rf][cf] = f32x4{0.f, 0.f, 0.f, 0.f};
        const int sw = (l15 & 7) << 4;
#pragma unroll
        for (int p = 0; p < NPAIR; ++p) {
            const int base = bb + p * 8192;
#pragma unroll
            for (int ks = 0; ks < 4; ++ks) {
                const int cbyte = ks * 64 + lk * 2;
                bf16x8 a0 = *reinterpret_cast<const bf16x8*>(
                    &lds[base + ((l15 * 256 + cbyte) ^ sw)]);
                bf16x8 a1 = *reinterpret_cast<const bf16x8*>(
                    &lds[base + (((16 + l15) * 256 + cbyte) ^ sw)]);
                acc[0][0] = __builtin_amdgcn_mfma_f32_16x16x32_bf16(a0, bfr[p][ks][0], acc[0][0], 0, 0, 0);
                acc[0][1] = __builtin_amdgcn_mfma_f32_16x16x32_bf16(a0, bfr[p][ks][1], acc[0][1], 0, 0, 0);
                acc[1][0] = __builtin_amdgcn_mfma_f32_16x16x32_bf16(a1, bfr[p][ks][0], acc[1][0], 0, 0, 0);
                acc[1][1] = __builtin_amdgcn_mfma_f32_16x16x32_bf16(a1, bfr[p][ks][1], acc[1][1], 0, 0, 0);
            }
        }

        const size_t rowbase = (size_t)tile * 32;
#pragma unroll
        for (int cf = 0; cf < 2; ++cf) {
            const int col = colbase + cf * 16 + l15;
            const float bv = cf ? bv1 : bv0;
#pragma unroll
            for (int rf = 0; rf < 2; ++rf) {
#pragma unroll
                for (int j = 0; j < 4; ++j) {
                    const size_t row = rowbase + rf * 16 + rq + j;
                    float vv = acc[rf][cf][j] + bv;
                    if (RELU) vv = fmaxf(vv, 0.f);
                    ob[row * OST + col] = f2b(vv);
                }
            }
        }

        if (nxt < NTILES) {                    // write staged regs into other buffer
            const int ob2 = (buf ^ 1) * NPAIR * 8192;
#pragma unroll
            for (int j = 0; j < NLOAD; ++j)
                *reinterpret_cast<uint4*>(&lds[ob2 + loff[j]]) = v[j];
        }
        __syncthreads();
        buf ^= 1;
        tile = nxt;
    }
}

// ---------------- register-B multi-pair MFMA GEMM (final N=64 GEMM) ----------------
template<int NPAIR, int COLGROUPS, int WAVES, bool RELU, bool OUTF32, bool DUAL>
__global__ __launch_bounds__(WAVES * 64, 2) void gemm_reg(
    const u16* __restrict__ A0, const u16* __restrict__ A1, const u16* __restrict__ A2,
    const u16* __restrict__ BT, const float* __restrict__ bias,
    float* __restrict__ outF, u16* __restrict__ outB, u16* __restrict__ outB2)
{
    constexpr int NC = COLGROUPS * 32;
    constexpr int RT = WAVES / COLGROUPS;
    constexpr int OST = DUAL ? (NC / 2) : NC;
    constexpr int NTILES = NN / 32;
    const int w = threadIdx.x >> 6, l = threadIdx.x & 63;
    const int cg = w % COLGROUPS, rsub = w / COLGROUPS;
    const int l15 = l & 15, lk = (l >> 4) << 3, rq = (l >> 4) << 2;

    bf16x8 bfr[NPAIR][4][2];
#pragma unroll
    for (int p = 0; p < NPAIR; ++p)
#pragma unroll
        for (int ks = 0; ks < 4; ++ks)
#pragma unroll
            for (int cf = 0; cf < 2; ++cf) {
                int n = p * NC + cg * 32 + cf * 16 + l15;
                bfr[p][ks][cf] = *reinterpret_cast<const bf16x8*>(BT + (size_t)n * 128 + ks * 32 + lk);
            }

    const u16* As[3] = {A0, A1, A2};
    const float bv0 = bias[cg * 32 + l15];
    const float bv1 = bias[cg * 32 + 16 + l15];

    for (int tile = blockIdx.x * RT + rsub; tile < NTILES; tile += gridDim.x * RT) {
        const size_t rowbase = (size_t)tile * 32;

        bf16x8 af[NPAIR][4][2];
#pragma unroll
        for (int p = 0; p < NPAIR; ++p) {
            const u16* A = As[p] + rowbase * 128;
#pragma unroll
            for (int ks = 0; ks < 4; ++ks) {
                const int k0 = ks * 32 + lk;
                af[p][ks][0] = *reinterpret_cast<const bf16x8*>(A + (size_t)l15 * 128 + k0);
                af[p][ks][1] = *reinterpret_cast<const bf16x8*>(A + (size_t)(16 + l15) * 128 + k0);
            }
        }

        f32x4 acc[2][2];
#pragma unroll
        for (int rf = 0; rf < 2; ++rf)
#pragma unroll
            for (int cf = 0; cf < 2; ++cf)
                acc[rf][cf] = f32x4{0.f, 0.f, 0.f, 0.f};

#pragma unroll
        for (int p = 0; p < NPAIR; ++p)
#pragma unroll
            for (int ks = 0; ks < 4; ++ks) {
                acc[0][0] = __builtin_amdgcn_mfma_f32_16x16x32_bf16(af[p][ks][0], bfr[p][ks][0], acc[0][0], 0, 0, 0);
                acc[0][1] = __builtin_amdgcn_mfma_f32_16x16x32_bf16(af[p][ks][0], bfr[p][ks][1], acc[0][1], 0, 0, 0);
                acc[1][0] = __builtin_amdgcn_mfma_f32_16x16x32_bf16(af[p][ks][1], bfr[p][ks][0], acc[1][0], 0, 0, 0);
                acc[1][1] = __builtin_amdgcn_mfma_f32_16x16x32_bf16(af[p][ks][1], bfr[p][ks][1], acc[1][1], 0, 0, 0);
            }

        u16* ob = outB;
        if (DUAL && cg >= 4) ob = outB2;
        const int colbase = (DUAL ? (cg & 3) : cg) * 32;
#pragma unroll
        for (int cf = 0; cf < 2; ++cf) {
            const int col = colbase + cf * 16 + l15;
            const float bv = cf ? bv1 : bv0;
#pragma unroll
            for (int rf = 0; rf < 2; ++rf) {
#pragma unroll
                for (int j = 0; j < 4; ++j) {
                    const size_t row = rowbase + rf * 16 + rq + j;
                    float v = acc[rf][cf][j] + bv;
                    if (RELU) v = fmaxf(v, 0.f);
                    if (OUTF32) outF[row * OST + col] = v;
                    else        ob[row * OST + col] = f2b(v);
                }
            }
        }
    }
}

extern "C" void kernel_launch(void* const* d_in, const int* in_sizes, int n_in,
                              void* d_out, int out_size, void* d_ws, size_t ws_size,
                              hipStream_t stream)
{
    const float* x     = (const float*)d_in[0];
    const int*   src0  = (const int*)d_in[1];
    const int*   dst0  = (const int*)d_in[2];
    const float* ew0   = (const float*)d_in[3];
    const int*   src1  = (const int*)d_in[4];
    const int*   dst1  = (const int*)d_in[5];
    const float* ew1   = (const float*)d_in[6];
    const float* Ws0_0 = (const float*)d_in[7];
    const float* Wn0_0 = (const float*)d_in[8];
    const float* b0_0  = (const float*)d_in[9];
    const float* Wp_0  = (const float*)d_in[10];
    const float* bp_0  = (const float*)d_in[11];
    const float* Ws1_0 = (const float*)d_in[12];
    const float* Wn1_0 = (const float*)d_in[13];
    const float* b1_0  = (const float*)d_in[14];
    const float* Ws0_1 = (const float*)d_in[15];
    const float* Wn0_1 = (const float*)d_in[16];
    const float* b0_1  = (const float*)d_in[17];
    const float* Wp_1  = (const float*)d_in[18];
    const float* bp_1  = (const float*)d_in[19];
    const float* Ws1_1 = (const float*)d_in[20];
    const float* Wn1_1 = (const float*)d_in[21];
    const float* b1_1  = (const float*)d_in[22];

    char* ws = (char*)d_ws;
    u16*   x16   = (u16*)(ws + 0);            // x bf16; reused as hp0 (bf16) later
    u16*   h16   = (u16*)(ws + 25600000);
    u16*   a0    = (u16*)(ws + 51200000);     // mean-agg r0; reused as max-agg r0
    u16*   a1    = (u16*)(ws + 76800000);     // mean-agg r1; reused as max-agg r1
    u16*   hp1   = (u16*)(ws + 102400000);    // hp r1 bf16
    u32*   csr0  = (u32*)(ws + 128000000);    // NE+8 packed entries
    u32*   csr1  = (u32*)(ws + 130400032);
    int*   offs0 = (int*)(ws + 132800064);
    int*   offs1 = (int*)(ws + 133200080);
    int*   cur0  = (int*)(ws + 133600096);
    int*   cur1  = (int*)(ws + 134000096);
    int*   deg0  = (int*)(ws + 134400096);
    int*   deg1  = (int*)(ws + 134800096);    // contiguous with deg0
    int*   bsA   = (int*)(ws + 135200096);
    int*   bsB   = (int*)(ws + 135200608);
    u16*   wts   = (u16*)(ws + 135201120);
    float* bsum0 = (float*)(ws + 135414112);
    float* bsum1 = (float*)(ws + 135414624);
    float* bpc   = (float*)(ws + 135415136);
    u8*    x8    = (u8*)(ws + 136000000);     // x fp8 table (12.8MB)

    u16* hp0 = x16;                           // x16 dead after layer-0 GEMM

    hipMemsetAsync(deg0, 0, 800000, stream);
    deg_part<<<2048, 256, 0, stream>>>(dst0, dst1, deg0, deg1);
    fused_setup<<<12918, 256, 0, stream>>>(
        x, x16, x8, Ws0_0, Ws0_1, Wn0_0, Wn0_1, Wp_0, Wp_1,
        Ws1_0, Ws1_1, Wn1_0, Wn1_1, b0_0, b0_1, b1_0, b1_1, bp_0, bp_1,
        wts, bsum0, bsum1, bpc);

    scan_local<<<196, 1024, 0, stream>>>(deg0, deg1, offs0, offs1, bsA, bsB);
    scan_bsums<<<2, 128, 0, stream>>>(bsA, bsB);
    scan_add<<<784, 256, 0, stream>>>(offs0, offs1, bsA, bsB, cur0, cur1, csr0, csr1);
    build_csr_part<<<2048, 256, 0, stream>>>(
        src0, dst0, ew0, src1, dst1, ew1, cur0, cur1, csr0, csr1);

    // ---- layer 0: mean gather over fp8 x-table; LDS-staged GEMM ----
    gather<false, true><<<50000, 256, 0, stream>>>(
        x8, x8, offs0, csr0, a0, offs1, csr1, a1);
    gemm_lds<3, 4, 4, true, false><<<768, 256, 0, stream>>>(
        x16, a0, a1, wts, bsum0, h16, nullptr);

    // ---- layer 1: LDS-staged dual Wp GEMM; max gather over bf16; final reg GEMM ----
    gemm_lds<1, 8, 8, true, true><<<768, 512, 0, stream>>>(
        h16, nullptr, nullptr, wts + 49152, bpc, hp0, hp1);
    gather<true, false><<<50000, 256, 0, stream>>>(
        (const u8*)hp0, (const u8*)hp1, offs0, csr0, a0, offs1, csr1, a1);
    gemm_reg<3, 2, 4, false, true, false><<<782, 256, 0, stream>>>(
        h16, a0, a1, wts + 81920, bsum1, (float*)d_out, nullptr, nullptr);
}